// Round 1
// baseline (1023.076 us; speedup 1.0000x reference)
//
#include <hip/hip_runtime.h>
#include <hip/hip_bf16.h>

#define B_ 2
#define S_ 1024
#define F_ 1024
#define H_ 8
#define D_ 64
#define R_ 2
#define BH (B_*H_)
#define NC 16
#define CL (S_/NC)

// ------------------------------------------------------------------
// Mask format sniffer + normalize to float 0/1.
// bool input may arrive as u8, i32, or f32. Detect by byte patterns in
// the first n bytes (safe under all interpretations).
// ------------------------------------------------------------------
__global__ void k_mask_prep(const void* __restrict__ mraw, float* __restrict__ maskf, int n) {
    __shared__ int fmt; // 0=int32, 1=byte, 2=float32
    int t = threadIdx.x;
    if (t == 0) fmt = 0;
    __syncthreads();
    const unsigned int* u32 = (const unsigned int*)mraw;
    for (int g = t; g < n / 4; g += blockDim.x) {
        unsigned int v = u32[g];
        if (v == 0x3F800000u) atomicMax(&fmt, 2);
        else if (v != 0u && v != 1u) atomicMax(&fmt, 1);
    }
    __syncthreads();
    int f = fmt;
    const unsigned char* u8 = (const unsigned char*)mraw;
    const float* f32 = (const float*)mraw;
    for (int i = t; i < n; i += blockDim.x) {
        float mv;
        if (f == 1)      mv = u8[i] ? 1.f : 0.f;
        else if (f == 2) mv = (f32[i] != 0.f) ? 1.f : 0.f;
        else             mv = (u32[i] != 0u) ? 1.f : 0.f;
        maskf[i] = mv;
    }
}

// ------------------------------------------------------------------
// fp32 GEMM: C[M,N] = A[M,K] @ W[K,N] (+bias). 128x128 tile, BK=16,
// 256 threads, 8x8 microtile. M%128==0, K%16==0; N guarded.
// ------------------------------------------------------------------
#define GBM 128
#define GBN 128
#define GBK 16

__global__ __launch_bounds__(256) void k_gemm_f32(
    const float* __restrict__ A, const float* __restrict__ W,
    const float* __restrict__ bias, float* __restrict__ C,
    int M, int N, int K)
{
    __shared__ float sA[GBK][GBM + 4];
    __shared__ float sW[GBK][GBN + 4];
    int t = threadIdx.x;
    int bm = blockIdx.y, bn = blockIdx.x;
    int r0 = (t >> 4) << 3;
    int c0 = (t & 15) << 3;
    int rowb = bm * GBM, colb = bn * GBN;
    float acc[8][8];
#pragma unroll
    for (int i = 0; i < 8; ++i)
#pragma unroll
        for (int j = 0; j < 8; ++j) acc[i][j] = 0.f;

    for (int k0 = 0; k0 < K; k0 += GBK) {
        __syncthreads();
#pragma unroll
        for (int it = 0; it < 2; ++it) {
            int f4 = t + it * 256;
            int ar = f4 >> 2;
            int ak = (f4 & 3) << 2;
            float4 av = *(const float4*)(A + (size_t)(rowb + ar) * K + k0 + ak);
            sA[ak + 0][ar] = av.x; sA[ak + 1][ar] = av.y;
            sA[ak + 2][ar] = av.z; sA[ak + 3][ar] = av.w;
        }
#pragma unroll
        for (int it = 0; it < 2; ++it) {
            int f4 = t + it * 256;
            int wk = f4 >> 5;
            int wc = (f4 & 31) << 2;
            int gc = colb + wc;
            float4 wv;
            if (gc + 3 < N) {
                wv = *(const float4*)(W + (size_t)(k0 + wk) * N + gc);
            } else {
                const float* wr = W + (size_t)(k0 + wk) * N;
                wv.x = (gc + 0 < N) ? wr[gc + 0] : 0.f;
                wv.y = (gc + 1 < N) ? wr[gc + 1] : 0.f;
                wv.z = (gc + 2 < N) ? wr[gc + 2] : 0.f;
                wv.w = (gc + 3 < N) ? wr[gc + 3] : 0.f;
            }
            *(float4*)&sW[wk][wc] = wv;
        }
        __syncthreads();
#pragma unroll
        for (int kk = 0; kk < GBK; ++kk) {
            float a[8], w[8];
            *(float4*)&a[0] = *(const float4*)&sA[kk][r0];
            *(float4*)&a[4] = *(const float4*)&sA[kk][r0 + 4];
            *(float4*)&w[0] = *(const float4*)&sW[kk][c0];
            *(float4*)&w[4] = *(const float4*)&sW[kk][c0 + 4];
#pragma unroll
            for (int i = 0; i < 8; ++i)
#pragma unroll
                for (int j = 0; j < 8; ++j)
                    acc[i][j] = fmaf(a[i], w[j], acc[i][j]);
        }
    }
#pragma unroll
    for (int i = 0; i < 8; ++i) {
        int gr = rowb + r0 + i;
#pragma unroll
        for (int j = 0; j < 8; ++j) {
            int gc = colb + c0 + j;
            if (gc < N) {
                float v = acc[i][j];
                if (bias) v += bias[gc];
                C[(size_t)gr * N + gc] = v;
            }
        }
    }
}

// ------------------------------------------------------------------
// silu then L2-normalize per contiguous group of 64 (in place).
// ------------------------------------------------------------------
__global__ void k_silu_norm(float* __restrict__ buf, int ngroups) {
    int w = threadIdx.x >> 6;
    int l = threadIdx.x & 63;
    int g = blockIdx.x * 4 + w;
    if (g >= ngroups) return;
    size_t idx = (size_t)g * 64 + l;
    float x = buf[idx];
    float s = x / (1.f + expf(-x));
    float ss = s * s;
#pragma unroll
    for (int m = 1; m < 64; m <<= 1) ss += __shfl_xor(ss, m);
    float nrm = sqrtf(ss) + 1e-6f;
    buf[idx] = s / nrm;
}

__global__ void k_sigmoid(float* __restrict__ buf, int n) {
    int i = blockIdx.x * blockDim.x + threadIdx.x;
    if (i < n) {
        float x = buf[i];
        buf[i] = 1.f / (1.f + expf(-x));
    }
}

// ------------------------------------------------------------------
// Phase 1: per (bh, chunk) compute transfer (A_c, B_c).
// Thread t: row i=t>>2, col group g=t&3 (cols g*16..g*16+15).
// A-state init I, B-state init 0; per token: scale by (1-mask), then
// r=0,1: u = St k; St += b*(v - u) k^T  (A-state uses v=0).
// ------------------------------------------------------------------
__global__ __launch_bounds__(256) void k_chunk_transfer(
    const float* __restrict__ kbuf, const float* __restrict__ vbuf,
    const float* __restrict__ bbuf, const float* __restrict__ maskf,
    float* __restrict__ Ac, float* __restrict__ Bc)
{
    int c = blockIdx.x;
    int bh = blockIdx.y;
    int b = bh >> 3, h = bh & 7;
    int t = threadIdx.x;
    int i = t >> 2, g = t & 3;
    __shared__ float sKV[4][64];
    __shared__ float sScal[4];
    float Ast[16], Bst[16];
#pragma unroll
    for (int jl = 0; jl < 16; ++jl) {
        Ast[jl] = (g * 16 + jl == i) ? 1.f : 0.f;
        Bst[jl] = 0.f;
    }
    int s0 = c * CL;
    for (int sl = 0; sl < CL; ++sl) {
        size_t tok = (size_t)(b * S_ + s0 + sl);
        __syncthreads();
        {
            int which = t >> 6, d = t & 63;
            const float* src;
            if (which == 0)      src = kbuf + tok * 1024 + h * 128;
            else if (which == 1) src = kbuf + tok * 1024 + h * 128 + 64;
            else if (which == 2) src = vbuf + tok * 1024 + h * 128;
            else                 src = vbuf + tok * 1024 + h * 128 + 64;
            sKV[which][d] = src[d];
            if (t == 0) {
                sScal[0] = bbuf[tok * 16 + h * 2 + 0];
                sScal[1] = bbuf[tok * 16 + h * 2 + 1];
                sScal[2] = 1.f - maskf[tok];
            }
        }
        __syncthreads();
        float m1 = sScal[2];
#pragma unroll
        for (int jl = 0; jl < 16; ++jl) { Ast[jl] *= m1; Bst[jl] *= m1; }
#pragma unroll
        for (int r = 0; r < 2; ++r) {
            float kk[16];
            *(float4*)&kk[0]  = *(const float4*)&sKV[r][g * 16];
            *(float4*)&kk[4]  = *(const float4*)&sKV[r][g * 16 + 4];
            *(float4*)&kk[8]  = *(const float4*)&sKV[r][g * 16 + 8];
            *(float4*)&kk[12] = *(const float4*)&sKV[r][g * 16 + 12];
            float vi = sKV[2 + r][i];
            float br = sScal[r];
            float uA = 0.f, uB = 0.f;
#pragma unroll
            for (int jl = 0; jl < 16; ++jl) {
                uA = fmaf(Ast[jl], kk[jl], uA);
                uB = fmaf(Bst[jl], kk[jl], uB);
            }
            uA += __shfl_xor(uA, 1); uA += __shfl_xor(uA, 2);
            uB += __shfl_xor(uB, 1); uB += __shfl_xor(uB, 2);
            float wA = -br * uA;
            float wB = br * (vi - uB);
#pragma unroll
            for (int jl = 0; jl < 16; ++jl) {
                Ast[jl] = fmaf(wA, kk[jl], Ast[jl]);
                Bst[jl] = fmaf(wB, kk[jl], Bst[jl]);
            }
        }
    }
    size_t base = ((size_t)bh * NC + c) * 4096 + (size_t)i * 64 + g * 16;
#pragma unroll
    for (int q4 = 0; q4 < 4; ++q4) {
        *(float4*)&Ac[base + q4 * 4] = *(float4*)&Ast[q4 * 4];
        *(float4*)&Bc[base + q4 * 4] = *(float4*)&Bst[q4 * 4];
    }
}

// ------------------------------------------------------------------
// Phase 2: sequential chunk combine per bh. S0 may alias Bc (Bc slot
// is consumed into acc before S0 is written). Emits final carry.
// ------------------------------------------------------------------
__global__ __launch_bounds__(1024) void k_combine(
    const float* __restrict__ Ac, const float* Bc,
    const float* __restrict__ carry, float* S0,
    float* __restrict__ carry_out)
{
    int bh = blockIdx.x;
    int t = threadIdx.x;
    __shared__ float sSt[64 * 64];
    __shared__ float sA[64 * 64];
    ((float4*)sSt)[t] = ((const float4*)(carry + (size_t)bh * 4096))[t];
    int i = t >> 4, j0 = (t & 15) * 4;
    for (int c = 0; c < NC; ++c) {
        __syncthreads();
        size_t cb = ((size_t)bh * NC + c) * 4096;
        float4 acc = ((const float4*)(Bc + cb))[t];       // consume Bc first
        ((float4*)sA)[t] = ((const float4*)(Ac + cb))[t];
        ((float4*)(S0 + cb))[t] = ((float4*)sSt)[t];      // chunk-start state
        __syncthreads();
#pragma unroll 4
        for (int p = 0; p < 64; ++p) {
            float stp = sSt[i * 64 + p];
            float4 a4 = *(const float4*)&sA[p * 64 + j0];
            acc.x = fmaf(stp, a4.x, acc.x);
            acc.y = fmaf(stp, a4.y, acc.y);
            acc.z = fmaf(stp, a4.z, acc.z);
            acc.w = fmaf(stp, a4.w, acc.w);
        }
        __syncthreads();
        ((float4*)sSt)[t] = acc;
    }
    __syncthreads();
    ((float4*)(carry_out + (size_t)bh * 4096))[t] = ((float4*)sSt)[t];
}

// ------------------------------------------------------------------
// Phase 3: per (bh, chunk) rerun recurrence from S0, emit x_s = St q_s.
// xbuf may alias qbuf (q[tok,h] read before x[tok,h] written, regions
// disjoint across blocks).
// ------------------------------------------------------------------
__global__ __launch_bounds__(256) void k_emit_x(
    const float* __restrict__ kbuf, const float* __restrict__ vbuf,
    const float* __restrict__ bbuf, const float* __restrict__ maskf,
    const float* qbuf, const float* __restrict__ S0,
    float* xbuf)
{
    int c = blockIdx.x;
    int bh = blockIdx.y;
    int b = bh >> 3, h = bh & 7;
    int t = threadIdx.x;
    int i = t >> 2, g = t & 3;
    __shared__ float sKV[4][64];
    __shared__ float sQ[64];
    __shared__ float sScal[4];
    float St[16];
    size_t sbase = ((size_t)bh * NC + c) * 4096 + (size_t)i * 64 + g * 16;
#pragma unroll
    for (int q4 = 0; q4 < 4; ++q4)
        *(float4*)&St[q4 * 4] = *(const float4*)&S0[sbase + q4 * 4];
    int s0 = c * CL;
    for (int sl = 0; sl < CL; ++sl) {
        size_t tok = (size_t)(b * S_ + s0 + sl);
        __syncthreads();
        {
            int which = t >> 6, d = t & 63;
            const float* src;
            if (which == 0)      src = kbuf + tok * 1024 + h * 128;
            else if (which == 1) src = kbuf + tok * 1024 + h * 128 + 64;
            else if (which == 2) src = vbuf + tok * 1024 + h * 128;
            else                 src = vbuf + tok * 1024 + h * 128 + 64;
            sKV[which][d] = src[d];
            if (t < 64) sQ[t] = qbuf[tok * 512 + h * 64 + t];
            if (t == 0) {
                sScal[0] = bbuf[tok * 16 + h * 2 + 0];
                sScal[1] = bbuf[tok * 16 + h * 2 + 1];
                sScal[2] = 1.f - maskf[tok];
            }
        }
        __syncthreads();
        float m1 = sScal[2];
#pragma unroll
        for (int jl = 0; jl < 16; ++jl) St[jl] *= m1;
#pragma unroll
        for (int r = 0; r < 2; ++r) {
            float kk[16];
            *(float4*)&kk[0]  = *(const float4*)&sKV[r][g * 16];
            *(float4*)&kk[4]  = *(const float4*)&sKV[r][g * 16 + 4];
            *(float4*)&kk[8]  = *(const float4*)&sKV[r][g * 16 + 8];
            *(float4*)&kk[12] = *(const float4*)&sKV[r][g * 16 + 12];
            float vi = sKV[2 + r][i];
            float br = sScal[r];
            float u = 0.f;
#pragma unroll
            for (int jl = 0; jl < 16; ++jl) u = fmaf(St[jl], kk[jl], u);
            u += __shfl_xor(u, 1); u += __shfl_xor(u, 2);
            float w = br * (vi - u);
#pragma unroll
            for (int jl = 0; jl < 16; ++jl) St[jl] = fmaf(w, kk[jl], St[jl]);
        }
        // x = St q (state after this token)
        float qq[16];
        *(float4*)&qq[0]  = *(const float4*)&sQ[g * 16];
        *(float4*)&qq[4]  = *(const float4*)&sQ[g * 16 + 4];
        *(float4*)&qq[8]  = *(const float4*)&sQ[g * 16 + 8];
        *(float4*)&qq[12] = *(const float4*)&sQ[g * 16 + 12];
        float xv = 0.f;
#pragma unroll
        for (int jl = 0; jl < 16; ++jl) xv = fmaf(St[jl], qq[jl], xv);
        xv += __shfl_xor(xv, 1); xv += __shfl_xor(xv, 2);
        if (g == 0) xbuf[tok * 512 + h * 64 + i] = xv;
    }
}

// ------------------------------------------------------------------
// RMS norm over rows of 512 (in place), * rms_scale.
// ------------------------------------------------------------------
__global__ void k_rms(float* __restrict__ x, const float* __restrict__ scale) {
    int w = threadIdx.x >> 6;
    int l = threadIdx.x & 63;
    size_t row = (size_t)blockIdx.x * 4 + w;
    float4 v0 = *(float4*)&x[row * 512 + l * 8];
    float4 v1 = *(float4*)&x[row * 512 + l * 8 + 4];
    float ss = v0.x * v0.x + v0.y * v0.y + v0.z * v0.z + v0.w * v0.w
             + v1.x * v1.x + v1.y * v1.y + v1.z * v1.z + v1.w * v1.w;
#pragma unroll
    for (int m = 1; m < 64; m <<= 1) ss += __shfl_xor(ss, m);
    float sc = rsqrtf(ss * (1.f / 512.f) + 1e-6f);
    float4 s0 = *(const float4*)&scale[l * 8];
    float4 s1 = *(const float4*)&scale[l * 8 + 4];
    v0.x *= sc * s0.x; v0.y *= sc * s0.y; v0.z *= sc * s0.z; v0.w *= sc * s0.w;
    v1.x *= sc * s1.x; v1.y *= sc * s1.y; v1.z *= sc * s1.z; v1.w *= sc * s1.w;
    *(float4*)&x[row * 512 + l * 8]     = v0;
    *(float4*)&x[row * 512 + l * 8 + 4] = v1;
}

// ------------------------------------------------------------------
extern "C" void kernel_launch(void* const* d_in, const int* in_sizes, int n_in,
                              void* d_out, int out_size, void* d_ws, size_t ws_size,
                              hipStream_t stream) {
    const float* inputs    = (const float*)d_in[0];
    const void*  mask      = d_in[1];
    const float* carry     = (const float*)d_in[2];
    const float* Wq        = (const float*)d_in[3];
    const float* Wk        = (const float*)d_in[4];
    const float* Wv        = (const float*)d_in[5];
    const float* Wb        = (const float*)d_in[6];
    const float* rms_scale = (const float*)d_in[7];
    const float* Wo        = (const float*)d_in[8];
    const float* bo        = (const float*)d_in[9];

    float* out_carry = (float*)d_out;                       // (B,H,D,D) = 65536
    float* out_y     = (float*)d_out + (size_t)B_ * H_ * D_ * D_;

    const int M = B_ * S_;  // 2048
    float* ws = (float*)d_ws;
    size_t o = 0;
    float* qb = ws + o; o += (size_t)M * 512;    // q (also reused as x)
    float* kb = ws + o; o += (size_t)M * 1024;
    float* vb = ws + o; o += (size_t)M * 1024;
    float* bb = ws + o; o += (size_t)M * 16;
    float* mf = ws + o; o += (size_t)M;
    float* Ac = ws + o; o += (size_t)BH * NC * 4096;
    float* Bc = ws + o; o += (size_t)BH * NC * 4096;  // also reused as S0
    float* S0 = Bc;
    float* xb = qb;

    k_mask_prep<<<1, 256, 0, stream>>>(mask, mf, M);

    k_gemm_f32<<<dim3(512 / 128, M / 128), 256, 0, stream>>>(inputs, Wq, nullptr, qb, M, 512, 1024);
    k_gemm_f32<<<dim3(1024 / 128, M / 128), 256, 0, stream>>>(inputs, Wk, nullptr, kb, M, 1024, 1024);
    k_gemm_f32<<<dim3(1024 / 128, M / 128), 256, 0, stream>>>(inputs, Wv, nullptr, vb, M, 1024, 1024);
    k_gemm_f32<<<dim3(1, M / 128), 256, 0, stream>>>(inputs, Wb, nullptr, bb, M, 16, 1024);

    k_silu_norm<<<(M * 8) / 4, 256, 0, stream>>>(qb, M * 8);
    k_silu_norm<<<(M * 16) / 4, 256, 0, stream>>>(kb, M * 16);
    k_sigmoid<<<(M * 16 + 255) / 256, 256, 0, stream>>>(bb, M * 16);

    k_chunk_transfer<<<dim3(NC, BH), 256, 0, stream>>>(kb, vb, bb, mf, Ac, Bc);
    k_combine<<<BH, 1024, 0, stream>>>(Ac, Bc, carry, S0, out_carry);
    k_emit_x<<<dim3(NC, BH), 256, 0, stream>>>(kb, vb, bb, mf, qb, S0, xb);

    k_rms<<<M / 4, 256, 0, stream>>>(xb, rms_scale);
    k_gemm_f32<<<dim3(1024 / 128, M / 128), 256, 0, stream>>>(xb, Wo, bo, out_y, M, 1024, 512);
}

// Round 2
// 372.918 us; speedup vs baseline: 2.7434x; 2.7434x over previous
//
#include <hip/hip_runtime.h>
#include <hip/hip_bf16.h>

#define B_ 2
#define S_ 1024
#define F_ 1024
#define H_ 8
#define D_ 64
#define R_ 2
#define BH (B_*H_)
#define NC 16
#define CL (S_/NC)

typedef __bf16 bf16x8 __attribute__((ext_vector_type(8)));
typedef unsigned short ushort8 __attribute__((ext_vector_type(8)));
typedef float f32x4 __attribute__((ext_vector_type(4)));

__device__ __forceinline__ unsigned short f2bf(float f) {
    unsigned u = __builtin_bit_cast(unsigned, f);
    unsigned r = u + 0x7FFFu + ((u >> 16) & 1u);
    return (unsigned short)(r >> 16);
}

__device__ __forceinline__ void gload_lds16(const void* g, void* l) {
    __builtin_amdgcn_global_load_lds(
        (const __attribute__((address_space(1))) void*)g,
        (__attribute__((address_space(3))) void*)l, 16, 0, 0);
}

// ------------------------------------------------------------------
// Mask format sniffer + normalize to float 0/1.
// ------------------------------------------------------------------
__global__ void k_mask_prep(const void* __restrict__ mraw, float* __restrict__ maskf, int n) {
    __shared__ int fmt; // 0=int32, 1=byte, 2=float32
    int t = threadIdx.x;
    if (t == 0) fmt = 0;
    __syncthreads();
    const unsigned int* u32 = (const unsigned int*)mraw;
    for (int g = t; g < n / 4; g += blockDim.x) {
        unsigned int v = u32[g];
        if (v == 0x3F800000u) atomicMax(&fmt, 2);
        else if (v != 0u && v != 1u) atomicMax(&fmt, 1);
    }
    __syncthreads();
    int f = fmt;
    const unsigned char* u8 = (const unsigned char*)mraw;
    const float* f32 = (const float*)mraw;
    for (int i = t; i < n; i += blockDim.x) {
        float mv;
        if (f == 1)      mv = u8[i] ? 1.f : 0.f;
        else if (f == 2) mv = (f32[i] != 0.f) ? 1.f : 0.f;
        else             mv = (u32[i] != 0u) ? 1.f : 0.f;
        maskf[i] = mv;
    }
}

// ------------------------------------------------------------------
// fp32 -> bf16 elementwise (n % 4 == 0)
// ------------------------------------------------------------------
__global__ void k_f32_to_bf16(const float* __restrict__ s, unsigned short* __restrict__ d, int n) {
    int i = (blockIdx.x * blockDim.x + threadIdx.x) * 4;
    if (i < n) {
        float4 v = *(const float4*)&s[i];
        d[i + 0] = f2bf(v.x); d[i + 1] = f2bf(v.y);
        d[i + 2] = f2bf(v.z); d[i + 3] = f2bf(v.w);
    }
}

// ------------------------------------------------------------------
// Transpose [K,N] f32 -> [N,K] bf16. 32x32 tiles, 256 threads.
// ------------------------------------------------------------------
__global__ __launch_bounds__(256) void k_transpose_to_bf16(
    const float* __restrict__ src, unsigned short* __restrict__ dst, int K, int N)
{
    __shared__ float tile[32][33];
    int bx = blockIdx.x, by = blockIdx.y;
    int tx = threadIdx.x & 31, ty = threadIdx.x >> 5;
#pragma unroll
    for (int i = 0; i < 32; i += 8)
        tile[ty + i][tx] = src[(size_t)(by * 32 + ty + i) * N + bx * 32 + tx];
    __syncthreads();
#pragma unroll
    for (int i = 0; i < 32; i += 8)
        dst[(size_t)(bx * 32 + ty + i) * K + by * 32 + tx] = f2bf(tile[tx][ty + i]);
}

// ------------------------------------------------------------------
// bf16 MFMA GEMM: C[M,N] = A[M,K] @ B[K,N] (+bias), A bf16 row-major,
// Bt = B^T bf16 [N,K] row-major, C fp32. Tile 128x64, BK=64, 4 waves.
// LDS XOR-swizzle (slot ^= row&7) applied via pre-swizzled global src
// (linear global_load_lds dest) + swizzled ds_read.
// ------------------------------------------------------------------
__global__ __launch_bounds__(256) void k_gemm_bf16(
    const unsigned short* __restrict__ A, const unsigned short* __restrict__ Bt,
    const float* __restrict__ bias, float* __restrict__ C,
    int M, int N, int K)
{
    constexpr int BM = 128, BN = 64, BK = 64;
    __shared__ unsigned short sA[BM * BK];
    __shared__ unsigned short sB[BN * BK];
    int t = threadIdx.x;
    int w = t >> 6, l = t & 63;
    int rowb = blockIdx.y * BM, colb = blockIdx.x * BN;
    int wr = w >> 1, wc = w & 1;      // 2x2 wave grid; wave tile 64x32
    int fr = l & 15, kgrp = l >> 4;   // fragment row/col, k-group

    f32x4 acc[4][2];
#pragma unroll
    for (int m = 0; m < 4; ++m)
#pragma unroll
        for (int n = 0; n < 2; ++n) acc[m][n] = (f32x4){0.f, 0.f, 0.f, 0.f};

    int lrow_off = l >> 3;      // row within an 8-row issue
    int kg_phys = l & 7;        // physical 16B slot

    for (int k0 = 0; k0 < K; k0 += BK) {
        __syncthreads();
        // stage A tile: 16 issues of 8 rows; 4 per wave
#pragma unroll
        for (int is = 0; is < 4; ++is) {
            int r0 = (w * 4 + is) * 8;
            int row = r0 + lrow_off;
            int kg_log = kg_phys ^ (row & 7);
            gload_lds16(A + (size_t)(rowb + row) * K + k0 + kg_log * 8, &sA[r0 * BK]);
        }
        // stage B tile: 8 issues; 2 per wave
#pragma unroll
        for (int is = 0; is < 2; ++is) {
            int r0 = (w * 2 + is) * 8;
            int row = r0 + lrow_off;
            int kg_log = kg_phys ^ (row & 7);
            gload_lds16(Bt + (size_t)(colb + row) * K + k0 + kg_log * 8, &sB[r0 * BK]);
        }
        asm volatile("s_waitcnt vmcnt(0)" ::: "memory");
        __syncthreads();

#pragma unroll
        for (int kk = 0; kk < BK; kk += 32) {
            int kg = (kk >> 3) + kgrp;  // logical k slot (0..7)
            bf16x8 af[4], bfv[2];
#pragma unroll
            for (int m = 0; m < 4; ++m) {
                int row = wr * 64 + m * 16 + fr;
                ushort8 raw = *(const ushort8*)&sA[row * BK + (kg ^ (row & 7)) * 8];
                af[m] = __builtin_bit_cast(bf16x8, raw);
            }
#pragma unroll
            for (int n = 0; n < 2; ++n) {
                int row = wc * 32 + n * 16 + fr;
                ushort8 raw = *(const ushort8*)&sB[row * BK + (kg ^ (row & 7)) * 8];
                bfv[n] = __builtin_bit_cast(bf16x8, raw);
            }
#pragma unroll
            for (int m = 0; m < 4; ++m)
#pragma unroll
                for (int n = 0; n < 2; ++n)
                    acc[m][n] = __builtin_amdgcn_mfma_f32_16x16x32_bf16(af[m], bfv[n], acc[m][n], 0, 0, 0);
        }
    }

#pragma unroll
    for (int m = 0; m < 4; ++m)
#pragma unroll
        for (int n = 0; n < 2; ++n) {
            int grow0 = rowb + wr * 64 + m * 16 + kgrp * 4;
            int gcol  = colb + wc * 32 + n * 16 + fr;
            float bv = bias ? bias[gcol] : 0.f;
#pragma unroll
            for (int r = 0; r < 4; ++r)
                C[(size_t)(grow0 + r) * N + gcol] = acc[m][n][r] + bv;
        }
}

// ------------------------------------------------------------------
// beta = sigmoid(inputs @ Wb): M=2048, N=16, K=1024. 16 rows/block.
// ------------------------------------------------------------------
__global__ __launch_bounds__(256) void k_beta(
    const float* __restrict__ in, const float* __restrict__ Wb, float* __restrict__ bb)
{
    int row = blockIdx.x * 16 + (threadIdx.x >> 4);
    int col = threadIdx.x & 15;
    const float* a = in + (size_t)row * 1024;
    float acc = 0.f;
#pragma unroll 4
    for (int k = 0; k < 1024; ++k)
        acc = fmaf(a[k], Wb[k * 16 + col], acc);
    bb[row * 16 + col] = 1.f / (1.f + expf(-acc));
}

// ------------------------------------------------------------------
// silu then L2-normalize per contiguous group of 64 (in place).
// ------------------------------------------------------------------
__global__ void k_silu_norm(float* __restrict__ buf, int ngroups) {
    int w = threadIdx.x >> 6;
    int l = threadIdx.x & 63;
    int g = blockIdx.x * 4 + w;
    if (g >= ngroups) return;
    size_t idx = (size_t)g * 64 + l;
    float x = buf[idx];
    float s = x / (1.f + expf(-x));
    float ss = s * s;
#pragma unroll
    for (int m = 1; m < 64; m <<= 1) ss += __shfl_xor(ss, m);
    float nrm = sqrtf(ss) + 1e-6f;
    buf[idx] = s / nrm;
}

// ------------------------------------------------------------------
// Phase 1: per (bh, chunk) transfer operators (A_c, B_c).
// ------------------------------------------------------------------
__global__ __launch_bounds__(256) void k_chunk_transfer(
    const float* __restrict__ kbuf, const float* __restrict__ vbuf,
    const float* __restrict__ bbuf, const float* __restrict__ maskf,
    float* __restrict__ Ac, float* __restrict__ Bc)
{
    int c = blockIdx.x;
    int bh = blockIdx.y;
    int b = bh >> 3, h = bh & 7;
    int t = threadIdx.x;
    int i = t >> 2, g = t & 3;
    __shared__ float sKV[4][64];
    __shared__ float sScal[4];
    float Ast[16], Bst[16];
#pragma unroll
    for (int jl = 0; jl < 16; ++jl) {
        Ast[jl] = (g * 16 + jl == i) ? 1.f : 0.f;
        Bst[jl] = 0.f;
    }
    int s0 = c * CL;
    for (int sl = 0; sl < CL; ++sl) {
        size_t tok = (size_t)(b * S_ + s0 + sl);
        __syncthreads();
        {
            int which = t >> 6, d = t & 63;
            const float* src;
            if (which == 0)      src = kbuf + tok * 1024 + h * 128;
            else if (which == 1) src = kbuf + tok * 1024 + h * 128 + 64;
            else if (which == 2) src = vbuf + tok * 1024 + h * 128;
            else                 src = vbuf + tok * 1024 + h * 128 + 64;
            sKV[which][d] = src[d];
            if (t == 0) {
                sScal[0] = bbuf[tok * 16 + h * 2 + 0];
                sScal[1] = bbuf[tok * 16 + h * 2 + 1];
                sScal[2] = 1.f - maskf[tok];
            }
        }
        __syncthreads();
        float m1 = sScal[2];
#pragma unroll
        for (int jl = 0; jl < 16; ++jl) { Ast[jl] *= m1; Bst[jl] *= m1; }
#pragma unroll
        for (int r = 0; r < 2; ++r) {
            float kk[16];
            *(float4*)&kk[0]  = *(const float4*)&sKV[r][g * 16];
            *(float4*)&kk[4]  = *(const float4*)&sKV[r][g * 16 + 4];
            *(float4*)&kk[8]  = *(const float4*)&sKV[r][g * 16 + 8];
            *(float4*)&kk[12] = *(const float4*)&sKV[r][g * 16 + 12];
            float vi = sKV[2 + r][i];
            float br = sScal[r];
            float uA = 0.f, uB = 0.f;
#pragma unroll
            for (int jl = 0; jl < 16; ++jl) {
                uA = fmaf(Ast[jl], kk[jl], uA);
                uB = fmaf(Bst[jl], kk[jl], uB);
            }
            uA += __shfl_xor(uA, 1); uA += __shfl_xor(uA, 2);
            uB += __shfl_xor(uB, 1); uB += __shfl_xor(uB, 2);
            float wA = -br * uA;
            float wB = br * (vi - uB);
#pragma unroll
            for (int jl = 0; jl < 16; ++jl) {
                Ast[jl] = fmaf(wA, kk[jl], Ast[jl]);
                Bst[jl] = fmaf(wB, kk[jl], Bst[jl]);
            }
        }
    }
    size_t base = ((size_t)bh * NC + c) * 4096 + (size_t)i * 64 + g * 16;
#pragma unroll
    for (int q4 = 0; q4 < 4; ++q4) {
        *(float4*)&Ac[base + q4 * 4] = *(float4*)&Ast[q4 * 4];
        *(float4*)&Bc[base + q4 * 4] = *(float4*)&Bst[q4 * 4];
    }
}

// ------------------------------------------------------------------
// Phase 2: sequential chunk combine per bh (S0 aliases Bc safely).
// ------------------------------------------------------------------
__global__ __launch_bounds__(1024) void k_combine(
    const float* __restrict__ Ac, const float* Bc,
    const float* __restrict__ carry, float* S0,
    float* __restrict__ carry_out)
{
    int bh = blockIdx.x;
    int t = threadIdx.x;
    __shared__ float sSt[64 * 64];
    __shared__ float sA[64 * 64];
    ((float4*)sSt)[t] = ((const float4*)(carry + (size_t)bh * 4096))[t];
    int i = t >> 4, j0 = (t & 15) * 4;
    for (int c = 0; c < NC; ++c) {
        __syncthreads();
        size_t cb = ((size_t)bh * NC + c) * 4096;
        float4 acc = ((const float4*)(Bc + cb))[t];
        ((float4*)sA)[t] = ((const float4*)(Ac + cb))[t];
        ((float4*)(S0 + cb))[t] = ((float4*)sSt)[t];
        __syncthreads();
#pragma unroll 4
        for (int p = 0; p < 64; ++p) {
            float stp = sSt[i * 64 + p];
            float4 a4 = *(const float4*)&sA[p * 64 + j0];
            acc.x = fmaf(stp, a4.x, acc.x);
            acc.y = fmaf(stp, a4.y, acc.y);
            acc.z = fmaf(stp, a4.z, acc.z);
            acc.w = fmaf(stp, a4.w, acc.w);
        }
        __syncthreads();
        ((float4*)sSt)[t] = acc;
    }
    __syncthreads();
    ((float4*)(carry_out + (size_t)bh * 4096))[t] = ((float4*)sSt)[t];
}

// ------------------------------------------------------------------
// Phase 3: rerun recurrence from S0, emit x_s = St q_s.
// ------------------------------------------------------------------
__global__ __launch_bounds__(256) void k_emit_x(
    const float* __restrict__ kbuf, const float* __restrict__ vbuf,
    const float* __restrict__ bbuf, const float* __restrict__ maskf,
    const float* qbuf, const float* __restrict__ S0,
    float* xbuf)
{
    int c = blockIdx.x;
    int bh = blockIdx.y;
    int b = bh >> 3, h = bh & 7;
    int t = threadIdx.x;
    int i = t >> 2, g = t & 3;
    __shared__ float sKV[4][64];
    __shared__ float sQ[64];
    __shared__ float sScal[4];
    float St[16];
    size_t sbase = ((size_t)bh * NC + c) * 4096 + (size_t)i * 64 + g * 16;
#pragma unroll
    for (int q4 = 0; q4 < 4; ++q4)
        *(float4*)&St[q4 * 4] = *(const float4*)&S0[sbase + q4 * 4];
    int s0 = c * CL;
    for (int sl = 0; sl < CL; ++sl) {
        size_t tok = (size_t)(b * S_ + s0 + sl);
        __syncthreads();
        {
            int which = t >> 6, d = t & 63;
            const float* src;
            if (which == 0)      src = kbuf + tok * 1024 + h * 128;
            else if (which == 1) src = kbuf + tok * 1024 + h * 128 + 64;
            else if (which == 2) src = vbuf + tok * 1024 + h * 128;
            else                 src = vbuf + tok * 1024 + h * 128 + 64;
            sKV[which][d] = src[d];
            if (t < 64) sQ[t] = qbuf[tok * 512 + h * 64 + t];
            if (t == 0) {
                sScal[0] = bbuf[tok * 16 + h * 2 + 0];
                sScal[1] = bbuf[tok * 16 + h * 2 + 1];
                sScal[2] = 1.f - maskf[tok];
            }
        }
        __syncthreads();
        float m1 = sScal[2];
#pragma unroll
        for (int jl = 0; jl < 16; ++jl) St[jl] *= m1;
#pragma unroll
        for (int r = 0; r < 2; ++r) {
            float kk[16];
            *(float4*)&kk[0]  = *(const float4*)&sKV[r][g * 16];
            *(float4*)&kk[4]  = *(const float4*)&sKV[r][g * 16 + 4];
            *(float4*)&kk[8]  = *(const float4*)&sKV[r][g * 16 + 8];
            *(float4*)&kk[12] = *(const float4*)&sKV[r][g * 16 + 12];
            float vi = sKV[2 + r][i];
            float br = sScal[r];
            float u = 0.f;
#pragma unroll
            for (int jl = 0; jl < 16; ++jl) u = fmaf(St[jl], kk[jl], u);
            u += __shfl_xor(u, 1); u += __shfl_xor(u, 2);
            float w = br * (vi - u);
#pragma unroll
            for (int jl = 0; jl < 16; ++jl) St[jl] = fmaf(w, kk[jl], St[jl]);
        }
        float qq[16];
        *(float4*)&qq[0]  = *(const float4*)&sQ[g * 16];
        *(float4*)&qq[4]  = *(const float4*)&sQ[g * 16 + 4];
        *(float4*)&qq[8]  = *(const float4*)&sQ[g * 16 + 8];
        *(float4*)&qq[12] = *(const float4*)&sQ[g * 16 + 12];
        float xv = 0.f;
#pragma unroll
        for (int jl = 0; jl < 16; ++jl) xv = fmaf(St[jl], qq[jl], xv);
        xv += __shfl_xor(xv, 1); xv += __shfl_xor(xv, 2);
        if (g == 0) xbuf[tok * 512 + h * 64 + i] = xv;
    }
}

// ------------------------------------------------------------------
// RMS norm over rows of 512, * rms_scale, emit bf16.
// ------------------------------------------------------------------
__global__ void k_rms_bf16(const float* __restrict__ x, const float* __restrict__ scale,
                           unsigned short* __restrict__ xo) {
    int w = threadIdx.x >> 6;
    int l = threadIdx.x & 63;
    size_t row = (size_t)blockIdx.x * 4 + w;
    float4 v0 = *(const float4*)&x[row * 512 + l * 8];
    float4 v1 = *(const float4*)&x[row * 512 + l * 8 + 4];
    float ss = v0.x * v0.x + v0.y * v0.y + v0.z * v0.z + v0.w * v0.w
             + v1.x * v1.x + v1.y * v1.y + v1.z * v1.z + v1.w * v1.w;
#pragma unroll
    for (int m = 1; m < 64; m <<= 1) ss += __shfl_xor(ss, m);
    float sc = rsqrtf(ss * (1.f / 512.f) + 1e-6f);
    float4 s0 = *(const float4*)&scale[l * 8];
    float4 s1 = *(const float4*)&scale[l * 8 + 4];
    ushort8 o;
    o[0] = f2bf(v0.x * sc * s0.x); o[1] = f2bf(v0.y * sc * s0.y);
    o[2] = f2bf(v0.z * sc * s0.z); o[3] = f2bf(v0.w * sc * s0.w);
    o[4] = f2bf(v1.x * sc * s1.x); o[5] = f2bf(v1.y * sc * s1.y);
    o[6] = f2bf(v1.z * sc * s1.z); o[7] = f2bf(v1.w * sc * s1.w);
    *(ushort8*)&xo[row * 512 + l * 8] = o;
}

// ------------------------------------------------------------------
extern "C" void kernel_launch(void* const* d_in, const int* in_sizes, int n_in,
                              void* d_out, int out_size, void* d_ws, size_t ws_size,
                              hipStream_t stream) {
    const float* inputs    = (const float*)d_in[0];
    const void*  mask      = d_in[1];
    const float* carry     = (const float*)d_in[2];
    const float* Wq        = (const float*)d_in[3];
    const float* Wk        = (const float*)d_in[4];
    const float* Wv        = (const float*)d_in[5];
    const float* Wb        = (const float*)d_in[6];
    const float* rms_scale = (const float*)d_in[7];
    const float* Wo        = (const float*)d_in[8];
    const float* bo        = (const float*)d_in[9];

    float* out_carry = (float*)d_out;
    float* out_y     = (float*)d_out + (size_t)B_ * H_ * D_ * D_;

    const int M = B_ * S_;  // 2048
    float* ws = (float*)d_ws;
    size_t o = 0;
    float* qb = ws + o; o += (size_t)M * 512;      // q (reused as x fp32)
    float* kb = ws + o; o += (size_t)M * 1024;
    float* vb = ws + o; o += (size_t)M * 1024;
    float* bb = ws + o; o += (size_t)M * 16;
    float* mf = ws + o; o += (size_t)M;
    float* Ac = ws + o; o += (size_t)BH * NC * 4096;
    float* Bc = ws + o; o += (size_t)BH * NC * 4096;   // reused as S0
    unsigned short* inb = (unsigned short*)(ws + o); o += (size_t)M * 512;   // 2M bf16
    unsigned short* wt  = (unsigned short*)(ws + o); o += (size_t)512 * 512; // 1M bf16
    unsigned short* xbf = (unsigned short*)(ws + o); o += (size_t)M * 256;   // 1M bf16
    float* S0 = Bc;
    float* xb = qb;

    k_mask_prep<<<1, 256, 0, stream>>>(mask, mf, M);
    k_f32_to_bf16<<<(M * 1024) / 1024, 256, 0, stream>>>(inputs, inb, M * 1024);

    // q = inputs @ Wq  (N=512)
    k_transpose_to_bf16<<<dim3(512 / 32, 1024 / 32), 256, 0, stream>>>(Wq, wt, 1024, 512);
    k_gemm_bf16<<<dim3(512 / 64, M / 128), 256, 0, stream>>>(inb, wt, nullptr, qb, M, 512, 1024);
    // k = inputs @ Wk  (N=1024)
    k_transpose_to_bf16<<<dim3(1024 / 32, 1024 / 32), 256, 0, stream>>>(Wk, wt, 1024, 1024);
    k_gemm_bf16<<<dim3(1024 / 64, M / 128), 256, 0, stream>>>(inb, wt, nullptr, kb, M, 1024, 1024);
    // v = inputs @ Wv
    k_transpose_to_bf16<<<dim3(1024 / 32, 1024 / 32), 256, 0, stream>>>(Wv, wt, 1024, 1024);
    k_gemm_bf16<<<dim3(1024 / 64, M / 128), 256, 0, stream>>>(inb, wt, nullptr, vb, M, 1024, 1024);
    // beta = sigmoid(inputs @ Wb)  (N=16, fp32 SIMT, sigmoid fused)
    k_beta<<<M / 16, 256, 0, stream>>>(inputs, Wb, bb);

    k_silu_norm<<<(M * 8) / 4, 256, 0, stream>>>(qb, M * 8);
    k_silu_norm<<<(M * 16) / 4, 256, 0, stream>>>(kb, M * 16);

    k_chunk_transfer<<<dim3(NC, BH), 256, 0, stream>>>(kb, vb, bb, mf, Ac, Bc);
    k_combine<<<BH, 1024, 0, stream>>>(Ac, Bc, carry, S0, out_carry);
    k_emit_x<<<dim3(NC, BH), 256, 0, stream>>>(kb, vb, bb, mf, qb, S0, xb);

    k_rms_bf16<<<M / 4, 256, 0, stream>>>(xb, rms_scale, xbf);

    // y = x @ Wo + bo  (K=512, N=1024)
    k_transpose_to_bf16<<<dim3(1024 / 32, 512 / 32), 256, 0, stream>>>(Wo, wt, 512, 1024);
    k_gemm_bf16<<<dim3(1024 / 64, M / 128), 256, 0, stream>>>(xbf, wt, bo, out_y, M, 1024, 512);
}

// Round 3
// 277.102 us; speedup vs baseline: 3.6921x; 1.3458x over previous
//
#include <hip/hip_runtime.h>
#include <hip/hip_bf16.h>

#define B_ 2
#define S_ 1024
#define F_ 1024
#define H_ 8
#define D_ 64
#define R_ 2
#define BH (B_*H_)
#define NC 16
#define CL (S_/NC)

typedef __bf16 bf16x8 __attribute__((ext_vector_type(8)));
typedef unsigned short ushort8 __attribute__((ext_vector_type(8)));
typedef float f32x4 __attribute__((ext_vector_type(4)));

__device__ __forceinline__ unsigned short f2bf(float f) {
    unsigned u = __builtin_bit_cast(unsigned, f);
    unsigned r = u + 0x7FFFu + ((u >> 16) & 1u);
    return (unsigned short)(r >> 16);
}

__device__ __forceinline__ void gload_lds16(const void* g, void* l) {
    __builtin_amdgcn_global_load_lds(
        (const __attribute__((address_space(1))) void*)g,
        (__attribute__((address_space(3))) void*)l, 16, 0, 0);
}

// ------------------------------------------------------------------
// Mask format sniffer + normalize to float 0/1.
// ------------------------------------------------------------------
__global__ void k_mask_prep(const void* __restrict__ mraw, float* __restrict__ maskf, int n) {
    __shared__ int fmt; // 0=int32, 1=byte, 2=float32
    int t = threadIdx.x;
    if (t == 0) fmt = 0;
    __syncthreads();
    const unsigned int* u32 = (const unsigned int*)mraw;
    for (int g = t; g < n / 4; g += blockDim.x) {
        unsigned int v = u32[g];
        if (v == 0x3F800000u) atomicMax(&fmt, 2);
        else if (v != 0u && v != 1u) atomicMax(&fmt, 1);
    }
    __syncthreads();
    int f = fmt;
    const unsigned char* u8 = (const unsigned char*)mraw;
    const float* f32 = (const float*)mraw;
    for (int i = t; i < n; i += blockDim.x) {
        float mv;
        if (f == 1)      mv = u8[i] ? 1.f : 0.f;
        else if (f == 2) mv = (f32[i] != 0.f) ? 1.f : 0.f;
        else             mv = (u32[i] != 0u) ? 1.f : 0.f;
        maskf[i] = mv;
    }
}

// ------------------------------------------------------------------
// fp32 -> bf16 elementwise (n % 4 == 0)
// ------------------------------------------------------------------
__global__ void k_f32_to_bf16(const float* __restrict__ s, unsigned short* __restrict__ d, int n) {
    int i = (blockIdx.x * blockDim.x + threadIdx.x) * 4;
    if (i < n) {
        float4 v = *(const float4*)&s[i];
        d[i + 0] = f2bf(v.x); d[i + 1] = f2bf(v.y);
        d[i + 2] = f2bf(v.z); d[i + 3] = f2bf(v.w);
    }
}

// ------------------------------------------------------------------
// Transpose [K,N] f32 -> [N,K] bf16. 32x32 tiles, 256 threads.
// ------------------------------------------------------------------
__global__ __launch_bounds__(256) void k_transpose_to_bf16(
    const float* __restrict__ src, unsigned short* __restrict__ dst, int K, int N)
{
    __shared__ float tile[32][33];
    int bx = blockIdx.x, by = blockIdx.y;
    int tx = threadIdx.x & 31, ty = threadIdx.x >> 5;
#pragma unroll
    for (int i = 0; i < 32; i += 8)
        tile[ty + i][tx] = src[(size_t)(by * 32 + ty + i) * N + bx * 32 + tx];
    __syncthreads();
#pragma unroll
    for (int i = 0; i < 32; i += 8)
        dst[(size_t)(bx * 32 + ty + i) * K + by * 32 + tx] = f2bf(tile[tx][ty + i]);
}

// ------------------------------------------------------------------
// bf16 MFMA GEMM: C[M,N] = A[M,K] @ B[K,N] (+bias). Tile 128x64, BK=64.
// ------------------------------------------------------------------
__global__ __launch_bounds__(256) void k_gemm_bf16(
    const unsigned short* __restrict__ A, const unsigned short* __restrict__ Bt,
    const float* __restrict__ bias, float* __restrict__ C,
    int M, int N, int K)
{
    constexpr int BM = 128, BN = 64, BK = 64;
    __shared__ unsigned short sA[BM * BK];
    __shared__ unsigned short sB[BN * BK];
    int t = threadIdx.x;
    int w = t >> 6, l = t & 63;
    int rowb = blockIdx.y * BM, colb = blockIdx.x * BN;
    int wr = w >> 1, wc = w & 1;
    int fr = l & 15, kgrp = l >> 4;

    f32x4 acc[4][2];
#pragma unroll
    for (int m = 0; m < 4; ++m)
#pragma unroll
        for (int n = 0; n < 2; ++n) acc[m][n] = (f32x4){0.f, 0.f, 0.f, 0.f};

    int lrow_off = l >> 3;
    int kg_phys = l & 7;

    for (int k0 = 0; k0 < K; k0 += BK) {
        __syncthreads();
#pragma unroll
        for (int is = 0; is < 4; ++is) {
            int r0 = (w * 4 + is) * 8;
            int row = r0 + lrow_off;
            int kg_log = kg_phys ^ (row & 7);
            gload_lds16(A + (size_t)(rowb + row) * K + k0 + kg_log * 8, &sA[r0 * BK]);
        }
#pragma unroll
        for (int is = 0; is < 2; ++is) {
            int r0 = (w * 2 + is) * 8;
            int row = r0 + lrow_off;
            int kg_log = kg_phys ^ (row & 7);
            gload_lds16(Bt + (size_t)(colb + row) * K + k0 + kg_log * 8, &sB[r0 * BK]);
        }
        asm volatile("s_waitcnt vmcnt(0)" ::: "memory");
        __syncthreads();

#pragma unroll
        for (int kk = 0; kk < BK; kk += 32) {
            int kg = (kk >> 3) + kgrp;
            bf16x8 af[4], bfv[2];
#pragma unroll
            for (int m = 0; m < 4; ++m) {
                int row = wr * 64 + m * 16 + fr;
                ushort8 raw = *(const ushort8*)&sA[row * BK + (kg ^ (row & 7)) * 8];
                af[m] = __builtin_bit_cast(bf16x8, raw);
            }
#pragma unroll
            for (int n = 0; n < 2; ++n) {
                int row = wc * 32 + n * 16 + fr;
                ushort8 raw = *(const ushort8*)&sB[row * BK + (kg ^ (row & 7)) * 8];
                bfv[n] = __builtin_bit_cast(bf16x8, raw);
            }
#pragma unroll
            for (int m = 0; m < 4; ++m)
#pragma unroll
                for (int n = 0; n < 2; ++n)
                    acc[m][n] = __builtin_amdgcn_mfma_f32_16x16x32_bf16(af[m], bfv[n], acc[m][n], 0, 0, 0);
        }
    }

#pragma unroll
    for (int m = 0; m < 4; ++m)
#pragma unroll
        for (int n = 0; n < 2; ++n) {
            int grow0 = rowb + wr * 64 + m * 16 + kgrp * 4;
            int gcol  = colb + wc * 32 + n * 16 + fr;
            float bv = bias ? bias[gcol] : 0.f;
#pragma unroll
            for (int r = 0; r < 4; ++r)
                C[(size_t)(grow0 + r) * N + gcol] = acc[m][n][r] + bv;
        }
}

// ------------------------------------------------------------------
// beta = sigmoid(inputs @ Wb): M=2048, N=16, K=1024.
// ------------------------------------------------------------------
__global__ __launch_bounds__(256) void k_beta(
    const float* __restrict__ in, const float* __restrict__ Wb, float* __restrict__ bb)
{
    int row = blockIdx.x * 16 + (threadIdx.x >> 4);
    int col = threadIdx.x & 15;
    const float* a = in + (size_t)row * 1024;
    float acc = 0.f;
#pragma unroll 4
    for (int k = 0; k < 1024; ++k)
        acc = fmaf(a[k], Wb[k * 16 + col], acc);
    bb[row * 16 + col] = 1.f / (1.f + expf(-acc));
}

// ------------------------------------------------------------------
// silu then L2-normalize per contiguous group of 64 (in place).
// ------------------------------------------------------------------
__global__ void k_silu_norm(float* __restrict__ buf, int ngroups) {
    int w = threadIdx.x >> 6;
    int l = threadIdx.x & 63;
    int g = blockIdx.x * 4 + w;
    if (g >= ngroups) return;
    size_t idx = (size_t)g * 64 + l;
    float x = buf[idx];
    float s = x / (1.f + expf(-x));
    float ss = s * s;
#pragma unroll
    for (int m = 1; m < 64; m <<= 1) ss += __shfl_xor(ss, m);
    float nrm = sqrtf(ss) + 1e-6f;
    buf[idx] = s / nrm;
}

// ------------------------------------------------------------------
// Phase 1: per (bh, chunk) transfer operators (A_c, B_c).
// Whole chunk staged into LDS up front; token loop is barrier-free
// and global-free. Thread t: row i=t>>2, k-group g=t&3.
// ------------------------------------------------------------------
__global__ __launch_bounds__(256) void k_chunk_transfer(
    const float* __restrict__ kbuf, const float* __restrict__ vbuf,
    const float* __restrict__ bbuf, const float* __restrict__ maskf,
    float* __restrict__ Ac, float* __restrict__ Bc)
{
    int c = blockIdx.x;
    int bh = blockIdx.y;
    int b = bh >> 3, h = bh & 7;
    int t = threadIdx.x;
    int i = t >> 2, g = t & 3;
    __shared__ float sK[CL][128];
    __shared__ float sV[CL][128];
    __shared__ float4 sScal[CL];   // {b0, b1, maskscale, pad}

    int s0 = c * CL;
    size_t tokbase = (size_t)(b * S_ + s0);
    // stage k, v: CL*128 floats = CL*32 float4 each -> 8 float4/thread
#pragma unroll
    for (int it = 0; it < (CL * 32) / 256; ++it) {
        int f = it * 256 + t;
        int tok = f >> 5, wi = f & 31;
        *(float4*)&sK[tok][wi * 4] = *(const float4*)&kbuf[(tokbase + tok) * 1024 + h * 128 + wi * 4];
        *(float4*)&sV[tok][wi * 4] = *(const float4*)&vbuf[(tokbase + tok) * 1024 + h * 128 + wi * 4];
    }
    if (t < CL) {
        float b0 = bbuf[(tokbase + t) * 16 + h * 2 + 0];
        float b1 = bbuf[(tokbase + t) * 16 + h * 2 + 1];
        float ms = 1.f - maskf[tokbase + t];
        sScal[t] = make_float4(b0, b1, ms, 0.f);
    }
    __syncthreads();

    float Ast[16], Bst[16];
#pragma unroll
    for (int jl = 0; jl < 16; ++jl) {
        Ast[jl] = (g * 16 + jl == i) ? 1.f : 0.f;
        Bst[jl] = 0.f;
    }

    for (int sl = 0; sl < CL; ++sl) {
        float4 sc = sScal[sl];
        float m1 = sc.z;
#pragma unroll
        for (int jl = 0; jl < 16; ++jl) { Ast[jl] *= m1; Bst[jl] *= m1; }
#pragma unroll
        for (int r = 0; r < 2; ++r) {
            float kk[16];
            *(float4*)&kk[0]  = *(const float4*)&sK[sl][r * 64 + g * 16];
            *(float4*)&kk[4]  = *(const float4*)&sK[sl][r * 64 + g * 16 + 4];
            *(float4*)&kk[8]  = *(const float4*)&sK[sl][r * 64 + g * 16 + 8];
            *(float4*)&kk[12] = *(const float4*)&sK[sl][r * 64 + g * 16 + 12];
            float vi = sV[sl][r * 64 + i];
            float br = (r == 0) ? sc.x : sc.y;
            // 4-way split reduction for latency
            float a0 = 0.f, a1 = 0.f, a2 = 0.f, a3 = 0.f;
            float b0 = 0.f, b1 = 0.f, b2 = 0.f, b3 = 0.f;
#pragma unroll
            for (int q = 0; q < 4; ++q) {
                a0 = fmaf(Ast[q],      kk[q],      a0);
                a1 = fmaf(Ast[4 + q],  kk[4 + q],  a1);
                a2 = fmaf(Ast[8 + q],  kk[8 + q],  a2);
                a3 = fmaf(Ast[12 + q], kk[12 + q], a3);
                b0 = fmaf(Bst[q],      kk[q],      b0);
                b1 = fmaf(Bst[4 + q],  kk[4 + q],  b1);
                b2 = fmaf(Bst[8 + q],  kk[8 + q],  b2);
                b3 = fmaf(Bst[12 + q], kk[12 + q], b3);
            }
            float uA = (a0 + a1) + (a2 + a3);
            float uB = (b0 + b1) + (b2 + b3);
            uA += __shfl_xor(uA, 1); uA += __shfl_xor(uA, 2);
            uB += __shfl_xor(uB, 1); uB += __shfl_xor(uB, 2);
            float wA = -br * uA;
            float wB = br * (vi - uB);
#pragma unroll
            for (int jl = 0; jl < 16; ++jl) {
                Ast[jl] = fmaf(wA, kk[jl], Ast[jl]);
                Bst[jl] = fmaf(wB, kk[jl], Bst[jl]);
            }
        }
    }
    size_t base = ((size_t)bh * NC + c) * 4096 + (size_t)i * 64 + g * 16;
#pragma unroll
    for (int q4 = 0; q4 < 4; ++q4) {
        *(float4*)&Ac[base + q4 * 4] = *(float4*)&Ast[q4 * 4];
        *(float4*)&Bc[base + q4 * 4] = *(float4*)&Bst[q4 * 4];
    }
}

// ------------------------------------------------------------------
// Phase 2: sequential chunk combine, split by state ROWS (rows evolve
// independently): 64 blocks = 16 bh x 4 row-groups of 16 rows.
// S0 aliases Bc (each thread reads its Bc element before writing S0).
// ------------------------------------------------------------------
__global__ __launch_bounds__(256) void k_combine(
    const float* __restrict__ Ac, const float* Bc,
    const float* __restrict__ carry, float* S0,
    float* __restrict__ carry_out)
{
    int blk = blockIdx.x;
    int bh = blk >> 2, rg = blk & 3;
    int t = threadIdx.x;
    int i = t >> 4;            // local row 0..15
    int j0 = (t & 15) * 4;     // col
    int gi = rg * 16 + i;      // global row
    __shared__ float sA[64 * 64];
    __shared__ float sS[16 * 64];

    *(float4*)&sS[i * 64 + j0] = *(const float4*)&carry[(size_t)bh * 4096 + gi * 64 + j0];

    for (int c = 0; c < NC; ++c) {
        size_t cb = ((size_t)bh * NC + c) * 4096;
        __syncthreads();   // sA reads from previous iter done
#pragma unroll
        for (int it = 0; it < 4; ++it) {
            int f = it * 256 + t;
            *(float4*)&sA[f * 4] = ((const float4*)(Ac + cb))[f];
        }
        float4 acc = *(const float4*)&Bc[cb + gi * 64 + j0];      // read Bc first
        float4 scur = *(float4*)&sS[i * 64 + j0];
        *(float4*)&S0[cb + gi * 64 + j0] = scur;                  // then write S0
        __syncthreads();
#pragma unroll 4
        for (int p = 0; p < 64; ++p) {
            float stp = sS[i * 64 + p];
            float4 a4 = *(const float4*)&sA[p * 64 + j0];
            acc.x = fmaf(stp, a4.x, acc.x);
            acc.y = fmaf(stp, a4.y, acc.y);
            acc.z = fmaf(stp, a4.z, acc.z);
            acc.w = fmaf(stp, a4.w, acc.w);
        }
        __syncthreads();
        *(float4*)&sS[i * 64 + j0] = acc;
    }
    __syncthreads();
    *(float4*)&carry_out[(size_t)bh * 4096 + gi * 64 + j0] = *(float4*)&sS[i * 64 + j0];
}

// ------------------------------------------------------------------
// Phase 3: rerun recurrence from S0, emit x_s = St q_s.
// Whole chunk staged; token loop barrier-free and global-load-free.
// ------------------------------------------------------------------
__global__ __launch_bounds__(256) void k_emit_x(
    const float* __restrict__ kbuf, const float* __restrict__ vbuf,
    const float* __restrict__ bbuf, const float* __restrict__ maskf,
    const float* qbuf, const float* __restrict__ S0,
    float* xbuf)
{
    int c = blockIdx.x;
    int bh = blockIdx.y;
    int b = bh >> 3, h = bh & 7;
    int t = threadIdx.x;
    int i = t >> 2, g = t & 3;
    __shared__ float sK[CL][128];
    __shared__ float sV[CL][128];
    __shared__ float sQ[CL][64];
    __shared__ float4 sScal[CL];

    int s0 = c * CL;
    size_t tokbase = (size_t)(b * S_ + s0);
#pragma unroll
    for (int it = 0; it < (CL * 32) / 256; ++it) {
        int f = it * 256 + t;
        int tok = f >> 5, wi = f & 31;
        *(float4*)&sK[tok][wi * 4] = *(const float4*)&kbuf[(tokbase + tok) * 1024 + h * 128 + wi * 4];
        *(float4*)&sV[tok][wi * 4] = *(const float4*)&vbuf[(tokbase + tok) * 1024 + h * 128 + wi * 4];
    }
#pragma unroll
    for (int it = 0; it < (CL * 16) / 256; ++it) {
        int f = it * 256 + t;
        int tok = f >> 4, wi = f & 15;
        *(float4*)&sQ[tok][wi * 4] = *(const float4*)&qbuf[(tokbase + tok) * 512 + h * 64 + wi * 4];
    }
    if (t < CL) {
        float b0 = bbuf[(tokbase + t) * 16 + h * 2 + 0];
        float b1 = bbuf[(tokbase + t) * 16 + h * 2 + 1];
        float ms = 1.f - maskf[tokbase + t];
        sScal[t] = make_float4(b0, b1, ms, 0.f);
    }
    __syncthreads();

    float St[16];
    size_t sbase = ((size_t)bh * NC + c) * 4096 + (size_t)i * 64 + g * 16;
#pragma unroll
    for (int q4 = 0; q4 < 4; ++q4)
        *(float4*)&St[q4 * 4] = *(const float4*)&S0[sbase + q4 * 4];

    for (int sl = 0; sl < CL; ++sl) {
        float4 sc = sScal[sl];
        float m1 = sc.z;
#pragma unroll
        for (int jl = 0; jl < 16; ++jl) St[jl] *= m1;
#pragma unroll
        for (int r = 0; r < 2; ++r) {
            float kk[16];
            *(float4*)&kk[0]  = *(const float4*)&sK[sl][r * 64 + g * 16];
            *(float4*)&kk[4]  = *(const float4*)&sK[sl][r * 64 + g * 16 + 4];
            *(float4*)&kk[8]  = *(const float4*)&sK[sl][r * 64 + g * 16 + 8];
            *(float4*)&kk[12] = *(const float4*)&sK[sl][r * 64 + g * 16 + 12];
            float vi = sV[sl][r * 64 + i];
            float br = (r == 0) ? sc.x : sc.y;
            float a0 = 0.f, a1 = 0.f, a2 = 0.f, a3 = 0.f;
#pragma unroll
            for (int q = 0; q < 4; ++q) {
                a0 = fmaf(St[q],      kk[q],      a0);
                a1 = fmaf(St[4 + q],  kk[4 + q],  a1);
                a2 = fmaf(St[8 + q],  kk[8 + q],  a2);
                a3 = fmaf(St[12 + q], kk[12 + q], a3);
            }
            float u = (a0 + a1) + (a2 + a3);
            u += __shfl_xor(u, 1); u += __shfl_xor(u, 2);
            float w = br * (vi - u);
#pragma unroll
            for (int jl = 0; jl < 16; ++jl) St[jl] = fmaf(w, kk[jl], St[jl]);
        }
        float qq[16];
        *(float4*)&qq[0]  = *(const float4*)&sQ[sl][g * 16];
        *(float4*)&qq[4]  = *(const float4*)&sQ[sl][g * 16 + 4];
        *(float4*)&qq[8]  = *(const float4*)&sQ[sl][g * 16 + 8];
        *(float4*)&qq[12] = *(const float4*)&sQ[sl][g * 16 + 12];
        float x0 = 0.f, x1 = 0.f, x2 = 0.f, x3 = 0.f;
#pragma unroll
        for (int q = 0; q < 4; ++q) {
            x0 = fmaf(St[q],      qq[q],      x0);
            x1 = fmaf(St[4 + q],  qq[4 + q],  x1);
            x2 = fmaf(St[8 + q],  qq[8 + q],  x2);
            x3 = fmaf(St[12 + q], qq[12 + q], x3);
        }
        float xv = (x0 + x1) + (x2 + x3);
        xv += __shfl_xor(xv, 1); xv += __shfl_xor(xv, 2);
        if (g == 0) xbuf[(tokbase + sl) * 512 + h * 64 + i] = xv;
    }
}

// ------------------------------------------------------------------
// RMS norm over rows of 512, * rms_scale, emit bf16.
// ------------------------------------------------------------------
__global__ void k_rms_bf16(const float* __restrict__ x, const float* __restrict__ scale,
                           unsigned short* __restrict__ xo) {
    int w = threadIdx.x >> 6;
    int l = threadIdx.x & 63;
    size_t row = (size_t)blockIdx.x * 4 + w;
    float4 v0 = *(const float4*)&x[row * 512 + l * 8];
    float4 v1 = *(const float4*)&x[row * 512 + l * 8 + 4];
    float ss = v0.x * v0.x + v0.y * v0.y + v0.z * v0.z + v0.w * v0.w
             + v1.x * v1.x + v1.y * v1.y + v1.z * v1.z + v1.w * v1.w;
#pragma unroll
    for (int m = 1; m < 64; m <<= 1) ss += __shfl_xor(ss, m);
    float sc = rsqrtf(ss * (1.f / 512.f) + 1e-6f);
    float4 s0 = *(const float4*)&scale[l * 8];
    float4 s1 = *(const float4*)&scale[l * 8 + 4];
    ushort8 o;
    o[0] = f2bf(v0.x * sc * s0.x); o[1] = f2bf(v0.y * sc * s0.y);
    o[2] = f2bf(v0.z * sc * s0.z); o[3] = f2bf(v0.w * sc * s0.w);
    o[4] = f2bf(v1.x * sc * s1.x); o[5] = f2bf(v1.y * sc * s1.y);
    o[6] = f2bf(v1.z * sc * s1.z); o[7] = f2bf(v1.w * sc * s1.w);
    *(ushort8*)&xo[row * 512 + l * 8] = o;
}

// ------------------------------------------------------------------
extern "C" void kernel_launch(void* const* d_in, const int* in_sizes, int n_in,
                              void* d_out, int out_size, void* d_ws, size_t ws_size,
                              hipStream_t stream) {
    const float* inputs    = (const float*)d_in[0];
    const void*  mask      = d_in[1];
    const float* carry     = (const float*)d_in[2];
    const float* Wq        = (const float*)d_in[3];
    const float* Wk        = (const float*)d_in[4];
    const float* Wv        = (const float*)d_in[5];
    const float* Wb        = (const float*)d_in[6];
    const float* rms_scale = (const float*)d_in[7];
    const float* Wo        = (const float*)d_in[8];
    const float* bo        = (const float*)d_in[9];

    float* out_carry = (float*)d_out;
    float* out_y     = (float*)d_out + (size_t)B_ * H_ * D_ * D_;

    const int M = B_ * S_;  // 2048
    float* ws = (float*)d_ws;
    size_t o = 0;
    float* qb = ws + o; o += (size_t)M * 512;      // q (reused as x fp32)
    float* kb = ws + o; o += (size_t)M * 1024;
    float* vb = ws + o; o += (size_t)M * 1024;
    float* bb = ws + o; o += (size_t)M * 16;
    float* mf = ws + o; o += (size_t)M;
    float* Ac = ws + o; o += (size_t)BH * NC * 4096;
    float* Bc = ws + o; o += (size_t)BH * NC * 4096;   // reused as S0
    unsigned short* inb = (unsigned short*)(ws + o); o += (size_t)M * 512;
    unsigned short* wt  = (unsigned short*)(ws + o); o += (size_t)512 * 512;
    unsigned short* xbf = (unsigned short*)(ws + o); o += (size_t)M * 256;
    float* S0 = Bc;
    float* xb = qb;

    k_mask_prep<<<1, 256, 0, stream>>>(mask, mf, M);
    k_f32_to_bf16<<<(M * 1024) / 1024, 256, 0, stream>>>(inputs, inb, M * 1024);

    // q = inputs @ Wq  (N=512)
    k_transpose_to_bf16<<<dim3(512 / 32, 1024 / 32), 256, 0, stream>>>(Wq, wt, 1024, 512);
    k_gemm_bf16<<<dim3(512 / 64, M / 128), 256, 0, stream>>>(inb, wt, nullptr, qb, M, 512, 1024);
    // k = inputs @ Wk  (N=1024)
    k_transpose_to_bf16<<<dim3(1024 / 32, 1024 / 32), 256, 0, stream>>>(Wk, wt, 1024, 1024);
    k_gemm_bf16<<<dim3(1024 / 64, M / 128), 256, 0, stream>>>(inb, wt, nullptr, kb, M, 1024, 1024);
    // v = inputs @ Wv
    k_transpose_to_bf16<<<dim3(1024 / 32, 1024 / 32), 256, 0, stream>>>(Wv, wt, 1024, 1024);
    k_gemm_bf16<<<dim3(1024 / 64, M / 128), 256, 0, stream>>>(inb, wt, nullptr, vb, M, 1024, 1024);
    // beta = sigmoid(inputs @ Wb)
    k_beta<<<M / 16, 256, 0, stream>>>(inputs, Wb, bb);

    k_silu_norm<<<(M * 8) / 4, 256, 0, stream>>>(qb, M * 8);
    k_silu_norm<<<(M * 16) / 4, 256, 0, stream>>>(kb, M * 16);

    k_chunk_transfer<<<dim3(NC, BH), 256, 0, stream>>>(kb, vb, bb, mf, Ac, Bc);
    k_combine<<<BH * 4, 256, 0, stream>>>(Ac, Bc, carry, S0, out_carry);
    k_emit_x<<<dim3(NC, BH), 256, 0, stream>>>(kb, vb, bb, mf, qb, S0, xb);

    k_rms_bf16<<<M / 4, 256, 0, stream>>>(xb, rms_scale, xbf);

    // y = x @ Wo + bo  (K=512, N=1024)
    k_transpose_to_bf16<<<dim3(1024 / 32, 512 / 32), 256, 0, stream>>>(Wo, wt, 512, 1024);
    k_gemm_bf16<<<dim3(1024 / 64, M / 128), 256, 0, stream>>>(xbf, wt, bo, out_y, M, 1024, 512);
}

// Round 4
// 182.272 us; speedup vs baseline: 5.6129x; 1.5203x over previous
//
#include <hip/hip_runtime.h>
#include <hip/hip_bf16.h>

#define B_ 2
#define S_ 1024
#define F_ 1024
#define H_ 8
#define D_ 64
#define R_ 2
#define BH (B_*H_)
#define NC 16
#define CL (S_/NC)

// combined projection layout: [M, NPROJ] fp32
#define QOFF 0
#define KOFF 512
#define VOFF 1536
#define BOFF 2560
#define NPROJ 2624   // 41 * 64

typedef __bf16 bf16x8 __attribute__((ext_vector_type(8)));
typedef unsigned short ushort8 __attribute__((ext_vector_type(8)));
typedef float f32x4 __attribute__((ext_vector_type(4)));

__device__ __forceinline__ unsigned short f2bf(float f) {
    unsigned u = __builtin_bit_cast(unsigned, f);
    unsigned r = u + 0x7FFFu + ((u >> 16) & 1u);
    return (unsigned short)(r >> 16);
}

__device__ __forceinline__ void gload_lds16(const void* g, void* l) {
    __builtin_amdgcn_global_load_lds(
        (const __attribute__((address_space(1))) void*)g,
        (__attribute__((address_space(3))) void*)l, 16, 0, 0);
}

// ------------------------------------------------------------------
// Mask format sniffer + normalize to float 0/1.
// ------------------------------------------------------------------
__global__ void k_mask_prep(const void* __restrict__ mraw, float* __restrict__ maskf, int n) {
    __shared__ int fmt; // 0=int32, 1=byte, 2=float32
    int t = threadIdx.x;
    if (t == 0) fmt = 0;
    __syncthreads();
    const unsigned int* u32 = (const unsigned int*)mraw;
    for (int g = t; g < n / 4; g += blockDim.x) {
        unsigned int v = u32[g];
        if (v == 0x3F800000u) atomicMax(&fmt, 2);
        else if (v != 0u && v != 1u) atomicMax(&fmt, 1);
    }
    __syncthreads();
    int f = fmt;
    const unsigned char* u8 = (const unsigned char*)mraw;
    const float* f32 = (const float*)mraw;
    for (int i = t; i < n; i += blockDim.x) {
        float mv;
        if (f == 1)      mv = u8[i] ? 1.f : 0.f;
        else if (f == 2) mv = (f32[i] != 0.f) ? 1.f : 0.f;
        else             mv = (u32[i] != 0u) ? 1.f : 0.f;
        maskf[i] = mv;
    }
}

// ------------------------------------------------------------------
// fp32 -> bf16 elementwise (n % 4 == 0)
// ------------------------------------------------------------------
__global__ void k_f32_to_bf16(const float* __restrict__ s, unsigned short* __restrict__ d, int n) {
    int i = (blockIdx.x * blockDim.x + threadIdx.x) * 4;
    if (i < n) {
        float4 v = *(const float4*)&s[i];
        d[i + 0] = f2bf(v.x); d[i + 1] = f2bf(v.y);
        d[i + 2] = f2bf(v.z); d[i + 3] = f2bf(v.w);
    }
}

// ------------------------------------------------------------------
// Transpose [K,N] f32 -> [N,K] bf16. 32x32 tiles, 256 threads.
// ------------------------------------------------------------------
__global__ __launch_bounds__(256) void k_transpose_to_bf16(
    const float* __restrict__ src, unsigned short* __restrict__ dst, int K, int N)
{
    __shared__ float tile[32][33];
    int bx = blockIdx.x, by = blockIdx.y;
    int tx = threadIdx.x & 31, ty = threadIdx.x >> 5;
#pragma unroll
    for (int i = 0; i < 32; i += 8)
        tile[ty + i][tx] = src[(size_t)(by * 32 + ty + i) * N + bx * 32 + tx];
    __syncthreads();
#pragma unroll
    for (int i = 0; i < 32; i += 8)
        dst[(size_t)(bx * 32 + ty + i) * K + by * 32 + tx] = f2bf(tile[tx][ty + i]);
}

// ------------------------------------------------------------------
// Wb [1024,16] f32 -> rows BOFF..BOFF+63 of wt as [64,1024] bf16,
// rows 16..63 zero.
// ------------------------------------------------------------------
__global__ void k_wb_pad(const float* __restrict__ Wb, unsigned short* __restrict__ dst) {
    int row = blockIdx.x;          // 0..63
    int c0 = threadIdx.x * 4;      // 0..1020
#pragma unroll
    for (int c = c0; c < c0 + 4; ++c)
        dst[(size_t)row * 1024 + c] = (row < 16) ? f2bf(Wb[(size_t)c * 16 + row]) : (unsigned short)0;
}

// ------------------------------------------------------------------
// bf16 MFMA GEMM: C[M,N] = A[M,K] @ B[K,N] (+bias). Tile 128x64, BK=64.
// ------------------------------------------------------------------
__global__ __launch_bounds__(256) void k_gemm_bf16(
    const unsigned short* __restrict__ A, const unsigned short* __restrict__ Bt,
    const float* __restrict__ bias, float* __restrict__ C,
    int M, int N, int K)
{
    constexpr int BM = 128, BN = 64, BK = 64;
    __shared__ unsigned short sA[BM * BK];
    __shared__ unsigned short sB[BN * BK];
    int t = threadIdx.x;
    int w = t >> 6, l = t & 63;
    int rowb = blockIdx.y * BM, colb = blockIdx.x * BN;
    int wr = w >> 1, wc = w & 1;
    int fr = l & 15, kgrp = l >> 4;

    f32x4 acc[4][2];
#pragma unroll
    for (int m = 0; m < 4; ++m)
#pragma unroll
        for (int n = 0; n < 2; ++n) acc[m][n] = (f32x4){0.f, 0.f, 0.f, 0.f};

    int lrow_off = l >> 3;
    int kg_phys = l & 7;

    for (int k0 = 0; k0 < K; k0 += BK) {
        __syncthreads();
#pragma unroll
        for (int is = 0; is < 4; ++is) {
            int r0 = (w * 4 + is) * 8;
            int row = r0 + lrow_off;
            int kg_log = kg_phys ^ (row & 7);
            gload_lds16(A + (size_t)(rowb + row) * K + k0 + kg_log * 8, &sA[r0 * BK]);
        }
#pragma unroll
        for (int is = 0; is < 2; ++is) {
            int r0 = (w * 2 + is) * 8;
            int row = r0 + lrow_off;
            int kg_log = kg_phys ^ (row & 7);
            gload_lds16(Bt + (size_t)(colb + row) * K + k0 + kg_log * 8, &sB[r0 * BK]);
        }
        asm volatile("s_waitcnt vmcnt(0)" ::: "memory");
        __syncthreads();

#pragma unroll
        for (int kk = 0; kk < BK; kk += 32) {
            int kg = (kk >> 3) + kgrp;
            bf16x8 af[4], bfv[2];
#pragma unroll
            for (int m = 0; m < 4; ++m) {
                int row = wr * 64 + m * 16 + fr;
                ushort8 raw = *(const ushort8*)&sA[row * BK + (kg ^ (row & 7)) * 8];
                af[m] = __builtin_bit_cast(bf16x8, raw);
            }
#pragma unroll
            for (int n = 0; n < 2; ++n) {
                int row = wc * 32 + n * 16 + fr;
                ushort8 raw = *(const ushort8*)&sB[row * BK + (kg ^ (row & 7)) * 8];
                bfv[n] = __builtin_bit_cast(bf16x8, raw);
            }
#pragma unroll
            for (int m = 0; m < 4; ++m)
#pragma unroll
                for (int n = 0; n < 2; ++n)
                    acc[m][n] = __builtin_amdgcn_mfma_f32_16x16x32_bf16(af[m], bfv[n], acc[m][n], 0, 0, 0);
        }
    }

#pragma unroll
    for (int m = 0; m < 4; ++m)
#pragma unroll
        for (int n = 0; n < 2; ++n) {
            int grow0 = rowb + wr * 64 + m * 16 + kgrp * 4;
            int gcol  = colb + wc * 32 + n * 16 + fr;
            float bv = bias ? bias[gcol] : 0.f;
#pragma unroll
            for (int r = 0; r < 4; ++r)
                C[(size_t)(grow0 + r) * N + gcol] = acc[m][n][r] + bv;
        }
}

// ------------------------------------------------------------------
// silu then L2-normalize per group of 64 with strided row layout.
// group g: row = g >> gshift, col = coloff + (g & gmask)*64 + lane.
// ------------------------------------------------------------------
__global__ void k_silu_norm(float* __restrict__ buf, int ngroups,
                            int gshift, int gmask, int rowstride, int coloff) {
    int w = threadIdx.x >> 6;
    int l = threadIdx.x & 63;
    int g = blockIdx.x * 4 + w;
    if (g >= ngroups) return;
    size_t idx = (size_t)(g >> gshift) * rowstride + coloff + ((g & gmask) << 6) + l;
    float x = buf[idx];
    float s = x / (1.f + expf(-x));
    float ss = s * s;
#pragma unroll
    for (int m = 1; m < 64; m <<= 1) ss += __shfl_xor(ss, m);
    float nrm = sqrtf(ss) + 1e-6f;
    buf[idx] = s / nrm;
}

// ------------------------------------------------------------------
// Phase 1: per (bh, chunk) transfer operators (A_c, B_c).
// Whole chunk staged into LDS; token loop barrier- and global-free.
// ------------------------------------------------------------------
__global__ __launch_bounds__(256) void k_chunk_transfer(
    const float* __restrict__ proj, const float* __restrict__ maskf,
    float* __restrict__ Ac, float* __restrict__ Bc)
{
    int c = blockIdx.x;
    int bh = blockIdx.y;
    int b = bh >> 3, h = bh & 7;
    int t = threadIdx.x;
    int i = t >> 2, g = t & 3;
    __shared__ float sK[CL][128];
    __shared__ float sV[CL][128];
    __shared__ float4 sScal[CL];   // {b0, b1, maskscale, pad}

    int s0 = c * CL;
    size_t tokbase = (size_t)(b * S_ + s0);
#pragma unroll
    for (int it = 0; it < (CL * 32) / 256; ++it) {
        int f = it * 256 + t;
        int tok = f >> 5, wi = f & 31;
        *(float4*)&sK[tok][wi * 4] = *(const float4*)&proj[(tokbase + tok) * NPROJ + KOFF + h * 128 + wi * 4];
        *(float4*)&sV[tok][wi * 4] = *(const float4*)&proj[(tokbase + tok) * NPROJ + VOFF + h * 128 + wi * 4];
    }
    if (t < CL) {
        float r0 = proj[(tokbase + t) * NPROJ + BOFF + h * 2 + 0];
        float r1 = proj[(tokbase + t) * NPROJ + BOFF + h * 2 + 1];
        float ms = 1.f - maskf[tokbase + t];
        sScal[t] = make_float4(1.f / (1.f + expf(-r0)), 1.f / (1.f + expf(-r1)), ms, 0.f);
    }
    __syncthreads();

    float Ast[16], Bst[16];
#pragma unroll
    for (int jl = 0; jl < 16; ++jl) {
        Ast[jl] = (g * 16 + jl == i) ? 1.f : 0.f;
        Bst[jl] = 0.f;
    }

    for (int sl = 0; sl < CL; ++sl) {
        float4 sc = sScal[sl];
        float m1 = sc.z;
#pragma unroll
        for (int jl = 0; jl < 16; ++jl) { Ast[jl] *= m1; Bst[jl] *= m1; }
#pragma unroll
        for (int r = 0; r < 2; ++r) {
            float kk[16];
            *(float4*)&kk[0]  = *(const float4*)&sK[sl][r * 64 + g * 16];
            *(float4*)&kk[4]  = *(const float4*)&sK[sl][r * 64 + g * 16 + 4];
            *(float4*)&kk[8]  = *(const float4*)&sK[sl][r * 64 + g * 16 + 8];
            *(float4*)&kk[12] = *(const float4*)&sK[sl][r * 64 + g * 16 + 12];
            float vi = sV[sl][r * 64 + i];
            float br = (r == 0) ? sc.x : sc.y;
            float a0 = 0.f, a1 = 0.f, a2 = 0.f, a3 = 0.f;
            float b0 = 0.f, b1 = 0.f, b2 = 0.f, b3 = 0.f;
#pragma unroll
            for (int q = 0; q < 4; ++q) {
                a0 = fmaf(Ast[q],      kk[q],      a0);
                a1 = fmaf(Ast[4 + q],  kk[4 + q],  a1);
                a2 = fmaf(Ast[8 + q],  kk[8 + q],  a2);
                a3 = fmaf(Ast[12 + q], kk[12 + q], a3);
                b0 = fmaf(Bst[q],      kk[q],      b0);
                b1 = fmaf(Bst[4 + q],  kk[4 + q],  b1);
                b2 = fmaf(Bst[8 + q],  kk[8 + q],  b2);
                b3 = fmaf(Bst[12 + q], kk[12 + q], b3);
            }
            float uA = (a0 + a1) + (a2 + a3);
            float uB = (b0 + b1) + (b2 + b3);
            uA += __shfl_xor(uA, 1); uA += __shfl_xor(uA, 2);
            uB += __shfl_xor(uB, 1); uB += __shfl_xor(uB, 2);
            float wA = -br * uA;
            float wB = br * (vi - uB);
#pragma unroll
            for (int jl = 0; jl < 16; ++jl) {
                Ast[jl] = fmaf(wA, kk[jl], Ast[jl]);
                Bst[jl] = fmaf(wB, kk[jl], Bst[jl]);
            }
        }
    }
    size_t base = ((size_t)bh * NC + c) * 4096 + (size_t)i * 64 + g * 16;
#pragma unroll
    for (int q4 = 0; q4 < 4; ++q4) {
        *(float4*)&Ac[base + q4 * 4] = *(float4*)&Ast[q4 * 4];
        *(float4*)&Bc[base + q4 * 4] = *(float4*)&Bst[q4 * 4];
    }
}

// ------------------------------------------------------------------
// Phase 2: sequential chunk combine, split by state ROWS.
// 64 blocks = 16 bh x 4 row-groups of 16 rows. S0 aliases Bc.
// ------------------------------------------------------------------
__global__ __launch_bounds__(256) void k_combine(
    const float* __restrict__ Ac, const float* Bc,
    const float* __restrict__ carry, float* S0,
    float* __restrict__ carry_out)
{
    int blk = blockIdx.x;
    int bh = blk >> 2, rg = blk & 3;
    int t = threadIdx.x;
    int i = t >> 4;
    int j0 = (t & 15) * 4;
    int gi = rg * 16 + i;
    __shared__ float sA[64 * 64];
    __shared__ float sS[16 * 64];

    *(float4*)&sS[i * 64 + j0] = *(const float4*)&carry[(size_t)bh * 4096 + gi * 64 + j0];

    for (int c = 0; c < NC; ++c) {
        size_t cb = ((size_t)bh * NC + c) * 4096;
        __syncthreads();
#pragma unroll
        for (int it = 0; it < 4; ++it) {
            int f = it * 256 + t;
            *(float4*)&sA[f * 4] = ((const float4*)(Ac + cb))[f];
        }
        float4 acc = *(const float4*)&Bc[cb + gi * 64 + j0];
        float4 scur = *(float4*)&sS[i * 64 + j0];
        *(float4*)&S0[cb + gi * 64 + j0] = scur;
        __syncthreads();
#pragma unroll 4
        for (int p = 0; p < 64; ++p) {
            float stp = sS[i * 64 + p];
            float4 a4 = *(const float4*)&sA[p * 64 + j0];
            acc.x = fmaf(stp, a4.x, acc.x);
            acc.y = fmaf(stp, a4.y, acc.y);
            acc.z = fmaf(stp, a4.z, acc.z);
            acc.w = fmaf(stp, a4.w, acc.w);
        }
        __syncthreads();
        *(float4*)&sS[i * 64 + j0] = acc;
    }
    __syncthreads();
    *(float4*)&carry_out[(size_t)bh * 4096 + gi * 64 + j0] = *(float4*)&sS[i * 64 + j0];
}

// ------------------------------------------------------------------
// Phase 3: rerun recurrence from S0, emit x_s = St q_s into the q
// columns of proj (q staged to LDS before any write; disjoint
// rows/cols across blocks).
// ------------------------------------------------------------------
__global__ __launch_bounds__(256) void k_emit_x(
    float* __restrict__ proj, const float* __restrict__ maskf,
    const float* __restrict__ S0)
{
    int c = blockIdx.x;
    int bh = blockIdx.y;
    int b = bh >> 3, h = bh & 7;
    int t = threadIdx.x;
    int i = t >> 2, g = t & 3;
    __shared__ float sK[CL][128];
    __shared__ float sV[CL][128];
    __shared__ float sQ[CL][64];
    __shared__ float4 sScal[CL];

    int s0 = c * CL;
    size_t tokbase = (size_t)(b * S_ + s0);
#pragma unroll
    for (int it = 0; it < (CL * 32) / 256; ++it) {
        int f = it * 256 + t;
        int tok = f >> 5, wi = f & 31;
        *(float4*)&sK[tok][wi * 4] = *(const float4*)&proj[(tokbase + tok) * NPROJ + KOFF + h * 128 + wi * 4];
        *(float4*)&sV[tok][wi * 4] = *(const float4*)&proj[(tokbase + tok) * NPROJ + VOFF + h * 128 + wi * 4];
    }
#pragma unroll
    for (int it = 0; it < (CL * 16) / 256; ++it) {
        int f = it * 256 + t;
        int tok = f >> 4, wi = f & 15;
        *(float4*)&sQ[tok][wi * 4] = *(const float4*)&proj[(tokbase + tok) * NPROJ + QOFF + h * 64 + wi * 4];
    }
    if (t < CL) {
        float r0 = proj[(tokbase + t) * NPROJ + BOFF + h * 2 + 0];
        float r1 = proj[(tokbase + t) * NPROJ + BOFF + h * 2 + 1];
        float ms = 1.f - maskf[tokbase + t];
        sScal[t] = make_float4(1.f / (1.f + expf(-r0)), 1.f / (1.f + expf(-r1)), ms, 0.f);
    }
    __syncthreads();

    float St[16];
    size_t sbase = ((size_t)bh * NC + c) * 4096 + (size_t)i * 64 + g * 16;
#pragma unroll
    for (int q4 = 0; q4 < 4; ++q4)
        *(float4*)&St[q4 * 4] = *(const float4*)&S0[sbase + q4 * 4];

    for (int sl = 0; sl < CL; ++sl) {
        float4 sc = sScal[sl];
        float m1 = sc.z;
#pragma unroll
        for (int jl = 0; jl < 16; ++jl) St[jl] *= m1;
#pragma unroll
        for (int r = 0; r < 2; ++r) {
            float kk[16];
            *(float4*)&kk[0]  = *(const float4*)&sK[sl][r * 64 + g * 16];
            *(float4*)&kk[4]  = *(const float4*)&sK[sl][r * 64 + g * 16 + 4];
            *(float4*)&kk[8]  = *(const float4*)&sK[sl][r * 64 + g * 16 + 8];
            *(float4*)&kk[12] = *(const float4*)&sK[sl][r * 64 + g * 16 + 12];
            float vi = sV[sl][r * 64 + i];
            float br = (r == 0) ? sc.x : sc.y;
            float a0 = 0.f, a1 = 0.f, a2 = 0.f, a3 = 0.f;
#pragma unroll
            for (int q = 0; q < 4; ++q) {
                a0 = fmaf(St[q],      kk[q],      a0);
                a1 = fmaf(St[4 + q],  kk[4 + q],  a1);
                a2 = fmaf(St[8 + q],  kk[8 + q],  a2);
                a3 = fmaf(St[12 + q], kk[12 + q], a3);
            }
            float u = (a0 + a1) + (a2 + a3);
            u += __shfl_xor(u, 1); u += __shfl_xor(u, 2);
            float w = br * (vi - u);
#pragma unroll
            for (int jl = 0; jl < 16; ++jl) St[jl] = fmaf(w, kk[jl], St[jl]);
        }
        float qq[16];
        *(float4*)&qq[0]  = *(const float4*)&sQ[sl][g * 16];
        *(float4*)&qq[4]  = *(const float4*)&sQ[sl][g * 16 + 4];
        *(float4*)&qq[8]  = *(const float4*)&sQ[sl][g * 16 + 8];
        *(float4*)&qq[12] = *(const float4*)&sQ[sl][g * 16 + 12];
        float x0 = 0.f, x1 = 0.f, x2 = 0.f, x3 = 0.f;
#pragma unroll
        for (int q = 0; q < 4; ++q) {
            x0 = fmaf(St[q],      qq[q],      x0);
            x1 = fmaf(St[4 + q],  qq[4 + q],  x1);
            x2 = fmaf(St[8 + q],  qq[8 + q],  x2);
            x3 = fmaf(St[12 + q], qq[12 + q], x3);
        }
        float xv = (x0 + x1) + (x2 + x3);
        xv += __shfl_xor(xv, 1); xv += __shfl_xor(xv, 2);
        if (g == 0) proj[(tokbase + sl) * NPROJ + QOFF + h * 64 + i] = xv;
    }
}

// ------------------------------------------------------------------
// RMS norm over x = proj cols 0..511, * rms_scale, emit compact bf16.
// ------------------------------------------------------------------
__global__ void k_rms_bf16(const float* __restrict__ proj, const float* __restrict__ scale,
                           unsigned short* __restrict__ xo) {
    int w = threadIdx.x >> 6;
    int l = threadIdx.x & 63;
    size_t row = (size_t)blockIdx.x * 4 + w;
    float4 v0 = *(const float4*)&proj[row * NPROJ + l * 8];
    float4 v1 = *(const float4*)&proj[row * NPROJ + l * 8 + 4];
    float ss = v0.x * v0.x + v0.y * v0.y + v0.z * v0.z + v0.w * v0.w
             + v1.x * v1.x + v1.y * v1.y + v1.z * v1.z + v1.w * v1.w;
#pragma unroll
    for (int m = 1; m < 64; m <<= 1) ss += __shfl_xor(ss, m);
    float sc = rsqrtf(ss * (1.f / 512.f) + 1e-6f);
    float4 s0 = *(const float4*)&scale[l * 8];
    float4 s1 = *(const float4*)&scale[l * 8 + 4];
    ushort8 o;
    o[0] = f2bf(v0.x * sc * s0.x); o[1] = f2bf(v0.y * sc * s0.y);
    o[2] = f2bf(v0.z * sc * s0.z); o[3] = f2bf(v0.w * sc * s0.w);
    o[4] = f2bf(v1.x * sc * s1.x); o[5] = f2bf(v1.y * sc * s1.y);
    o[6] = f2bf(v1.z * sc * s1.z); o[7] = f2bf(v1.w * sc * s1.w);
    *(ushort8*)&xo[row * 512 + l * 8] = o;
}

// ------------------------------------------------------------------
extern "C" void kernel_launch(void* const* d_in, const int* in_sizes, int n_in,
                              void* d_out, int out_size, void* d_ws, size_t ws_size,
                              hipStream_t stream) {
    const float* inputs    = (const float*)d_in[0];
    const void*  mask      = d_in[1];
    const float* carry     = (const float*)d_in[2];
    const float* Wq        = (const float*)d_in[3];
    const float* Wk        = (const float*)d_in[4];
    const float* Wv        = (const float*)d_in[5];
    const float* Wb        = (const float*)d_in[6];
    const float* rms_scale = (const float*)d_in[7];
    const float* Wo        = (const float*)d_in[8];
    const float* bo        = (const float*)d_in[9];

    float* out_carry = (float*)d_out;
    float* out_y     = (float*)d_out + (size_t)B_ * H_ * D_ * D_;

    const int M = B_ * S_;  // 2048
    float* ws = (float*)d_ws;
    size_t o = 0;
    float* proj = ws + o; o += (size_t)M * NPROJ;              // 5.37M f32
    float* mf   = ws + o; o += (size_t)M;
    float* Ac   = ws + o; o += (size_t)BH * NC * 4096;
    float* Bc   = ws + o; o += (size_t)BH * NC * 4096;         // reused as S0
    unsigned short* inb = (unsigned short*)(ws + o); o += (size_t)M * 512;       // M*1024 bf16
    unsigned short* wt  = (unsigned short*)(ws + o); o += (size_t)NPROJ * 512;   // NPROJ*1024 bf16
    unsigned short* xbf = (unsigned short*)(ws + o); o += (size_t)M * 256;       // M*512 bf16
    float* S0 = Bc;

    k_mask_prep<<<1, 256, 0, stream>>>(mask, mf, M);
    k_f32_to_bf16<<<(M * 1024) / 1024, 256, 0, stream>>>(inputs, inb, M * 1024);

    // pack W^T = [Wq^T | Wk^T | Wv^T | Wb^T(pad to 64)] as [NPROJ,1024] bf16
    k_transpose_to_bf16<<<dim3(512 / 32, 1024 / 32), 256, 0, stream>>>(Wq, wt + (size_t)QOFF * 1024, 1024, 512);
    k_transpose_to_bf16<<<dim3(1024 / 32, 1024 / 32), 256, 0, stream>>>(Wk, wt + (size_t)KOFF * 1024, 1024, 1024);
    k_transpose_to_bf16<<<dim3(1024 / 32, 1024 / 32), 256, 0, stream>>>(Wv, wt + (size_t)VOFF * 1024, 1024, 1024);
    k_wb_pad<<<64, 256, 0, stream>>>(Wb, wt + (size_t)BOFF * 1024);

    // proj = inputs @ [Wq|Wk|Wv|Wb]  (one MFMA GEMM, 41x16 = 656 blocks)
    k_gemm_bf16<<<dim3(NPROJ / 64, M / 128), 256, 0, stream>>>(inb, wt, nullptr, proj, M, NPROJ, 1024);

    // silu+L2norm on q (8 groups/row) and k (16 groups/row)
    k_silu_norm<<<(M * 8) / 4, 256, 0, stream>>>(proj, M * 8, 3, 7, NPROJ, QOFF);
    k_silu_norm<<<(M * 16) / 4, 256, 0, stream>>>(proj, M * 16, 4, 15, NPROJ, KOFF);

    k_chunk_transfer<<<dim3(NC, BH), 256, 0, stream>>>(proj, mf, Ac, Bc);
    k_combine<<<BH * 4, 256, 0, stream>>>(Ac, Bc, carry, S0, out_carry);
    k_emit_x<<<dim3(NC, BH), 256, 0, stream>>>(proj, mf, S0);

    k_rms_bf16<<<M / 4, 256, 0, stream>>>(proj, rms_scale, xbf);

    // y = x @ Wo + bo  (K=512, N=1024); reuse wt for Wo^T
    k_transpose_to_bf16<<<dim3(1024 / 32, 512 / 32), 256, 0, stream>>>(Wo, wt, 512, 1024);
    k_gemm_bf16<<<dim3(1024 / 64, M / 128), 256, 0, stream>>>(xbf, wt, bo, out_y, M, 1024, 512);
}